// Round 1
// baseline (484.287 us; speedup 1.0000x reference)
//
#include <hip/hip_runtime.h>

#define NH 1024   // hidden
#define NI2 2048  // 2*intermediate
#define NI 1024   // intermediate
#define NE 16     // experts
#define NT 1024   // tokens (2*512)

static constexpr float LIMITF = 7.0f;
static constexpr float ALPHAF = 1.702f;
static constexpr float EPSF = 1e-5f;

typedef short bf16x8 __attribute__((ext_vector_type(8)));
typedef float f32x4 __attribute__((ext_vector_type(4)));

__device__ __forceinline__ unsigned short f2bf(float f) {
  unsigned int u = __builtin_bit_cast(unsigned int, f);
  u = (u + 0x7FFFu + ((u >> 16) & 1u)) >> 16;
  return (unsigned short)u;
}

// ---------------- out = x (residual base) ----------------
__global__ __launch_bounds__(256) void k_init(const float* __restrict__ x,
                                              float* __restrict__ out) {
  int i = blockIdx.x * 256 + threadIdx.x;
  reinterpret_cast<float4*>(out)[i] = reinterpret_cast<const float4*>(x)[i];
}

// ---------------- RMSNorm + router ----------------
__global__ __launch_bounds__(256) void k_norm_router(
    const float* __restrict__ x, const float* __restrict__ nsc,
    const float* __restrict__ wg, const float* __restrict__ bg,
    unsigned short* __restrict__ xn, int* __restrict__ topk_idx,
    float* __restrict__ topk_gate, int* __restrict__ counts) {
  int t = blockIdx.x;
  int tid = threadIdx.x;
  int wave = tid >> 6, lane = tid & 63;

  float4 v = reinterpret_cast<const float4*>(x + (size_t)t * NH)[tid];
  float ss = v.x * v.x + v.y * v.y + v.z * v.z + v.w * v.w;
  for (int off = 32; off; off >>= 1) ss += __shfl_xor(ss, off);

  __shared__ float red[4];
  __shared__ float redl[4][16];
  __shared__ float logits_s[16];
  if (lane == 0) red[wave] = ss;
  __syncthreads();
  float tot = red[0] + red[1] + red[2] + red[3];
  float r = rsqrtf(tot * (1.0f / NH) + EPSF);

  float4 sc = reinterpret_cast<const float4*>(nsc)[tid];
  float xv[4];
  xv[0] = v.x * r * sc.x;
  xv[1] = v.y * r * sc.y;
  xv[2] = v.z * r * sc.z;
  xv[3] = v.w * r * sc.w;

  ushort4 o;
  o.x = f2bf(xv[0]); o.y = f2bf(xv[1]); o.z = f2bf(xv[2]); o.w = f2bf(xv[3]);
  reinterpret_cast<ushort4*>(xn + (size_t)t * NH)[tid] = o;

  // router logits: acc[e] += xn[h] * wg[h][e]
  float acc[16];
#pragma unroll
  for (int e = 0; e < 16; e++) acc[e] = 0.f;
  int hbase = tid * 4;
#pragma unroll
  for (int i = 0; i < 4; i++) {
    const float4* wr = reinterpret_cast<const float4*>(wg + (size_t)(hbase + i) * NE);
#pragma unroll
    for (int j = 0; j < 4; j++) {
      float4 w = wr[j];
      acc[j * 4 + 0] += xv[i] * w.x;
      acc[j * 4 + 1] += xv[i] * w.y;
      acc[j * 4 + 2] += xv[i] * w.z;
      acc[j * 4 + 3] += xv[i] * w.w;
    }
  }
#pragma unroll
  for (int e = 0; e < 16; e++)
    for (int off = 32; off; off >>= 1) acc[e] += __shfl_xor(acc[e], off);
  if (lane == 0) {
#pragma unroll
    for (int e = 0; e < 16; e++) redl[wave][e] = acc[e];
  }
  __syncthreads();
  if (tid < 16)
    logits_s[tid] = redl[0][tid] + redl[1][tid] + redl[2][tid] + redl[3][tid] + bg[tid];
  __syncthreads();

  if (tid == 0) {
    float vals[16];
#pragma unroll
    for (int e = 0; e < 16; e++) vals[e] = logits_s[e];
    int sel[4]; float sv[4];
    unsigned used = 0;
    for (int k = 0; k < 4; k++) {
      float best = -1e30f; int bi = 0;
      for (int e = 0; e < 16; e++) {
        if (!((used >> e) & 1u) && vals[e] > best) { best = vals[e]; bi = e; }
      }
      used |= 1u << bi; sel[k] = bi; sv[k] = best;
    }
    float g[4], ssum = 0.f;
    for (int k = 0; k < 4; k++) { g[k] = __expf(sv[k] - sv[0]); ssum += g[k]; }
    for (int k = 0; k < 4; k++) {
      topk_idx[t * 4 + k] = sel[k];
      topk_gate[t * 4 + k] = g[k] / ssum;
      atomicAdd(&counts[sel[k]], 1);
    }
  }
}

// ---------------- prefix scan over 16 experts ----------------
__global__ void k_scan(const int* __restrict__ counts, int* __restrict__ offsets,
                       int* __restrict__ cursor) {
  if (blockIdx.x == 0 && threadIdx.x == 0) {
    int o = 0;
    for (int e = 0; e < NE; e++) { offsets[e] = o; cursor[e] = o; o += counts[e]; }
  }
}

// ---------------- fill compact per-expert row lists ----------------
__global__ __launch_bounds__(256) void k_fill(const int* __restrict__ topk_idx,
                                              const float* __restrict__ topk_gate,
                                              int* __restrict__ cursor,
                                              int* __restrict__ rows_tok,
                                              float* __restrict__ rows_gate) {
  int idx = blockIdx.x * 256 + threadIdx.x;
  if (idx >= NT * 4) return;
  int e = topk_idx[idx];
  int slot = atomicAdd(&cursor[e], 1);
  rows_tok[slot] = idx >> 2;
  rows_gate[slot] = topk_gate[idx];
}

// ---------------- FFN1: h = xn @ w1 + b1 ; s = swiglu(h) ----------------
__global__ __launch_bounds__(256) void k_ffn1(
    const unsigned short* __restrict__ xn, const float* __restrict__ w1,
    const float* __restrict__ b1, const int* __restrict__ counts,
    const int* __restrict__ offsets, const int* __restrict__ rows_tok,
    unsigned short* __restrict__ s_buf) {
  int e = blockIdx.y;
  int cnt = counts[e];
  int m0 = blockIdx.z * 32;
  if (m0 >= cnt) return;
  int rowbase = offsets[e] + m0;
  int mcount = min(32, cnt - m0);
  int n0 = blockIdx.x * 64;
  int tid = threadIdx.x;

  __shared__ int tok_s[32];
  __shared__ __align__(16) unsigned short lds_a[32 * 32];
  __shared__ unsigned int lds_b[64 * 17];

  if (tid < 32) tok_s[tid] = rows_tok[rowbase + min(tid, mcount - 1)];
  __syncthreads();

  const int wave = tid >> 6, lane = tid & 63;
  const int quad = lane >> 4, l16 = lane & 15;
  const int m16 = (wave & 1) * 16;
  const int nw = (wave >> 1) * 32;

  f32x4 acc0 = {0.f, 0.f, 0.f, 0.f}, acc1 = {0.f, 0.f, 0.f, 0.f};

  const float* w1e = w1 + (size_t)e * NH * NI2 + n0;
  const int ar = tid >> 3, ac = (tid & 7) * 4;
  const int bn = tid & 63, bk0 = (tid >> 6) * 2;

  for (int k0 = 0; k0 < NH; k0 += 32) {
    uint2 av = *reinterpret_cast<const uint2*>(xn + (size_t)tok_s[ar] * NH + k0 + ac);
    *reinterpret_cast<uint2*>(&lds_a[ar * 32 + ac]) = av;
#pragma unroll
    for (int it = 0; it < 4; it++) {
      int kk = bk0 + it * 8;
      float f0 = w1e[(size_t)(k0 + kk) * NI2 + bn];
      float f1 = w1e[(size_t)(k0 + kk + 1) * NI2 + bn];
      lds_b[bn * 17 + (kk >> 1)] =
          (unsigned int)f2bf(f0) | ((unsigned int)f2bf(f1) << 16);
    }
    __syncthreads();
    bf16x8 a = *reinterpret_cast<const bf16x8*>(&lds_a[(m16 + l16) * 32 + quad * 8]);
    const unsigned int* bp0 = &lds_b[(nw + l16) * 17 + quad * 4];
    uint4 t0; t0.x = bp0[0]; t0.y = bp0[1]; t0.z = bp0[2]; t0.w = bp0[3];
    acc0 = __builtin_amdgcn_mfma_f32_16x16x32_bf16(
        a, __builtin_bit_cast(bf16x8, t0), acc0, 0, 0, 0);
    const unsigned int* bp1 = &lds_b[(nw + 16 + l16) * 17 + quad * 4];
    uint4 t1; t1.x = bp1[0]; t1.y = bp1[1]; t1.z = bp1[2]; t1.w = bp1[3];
    acc1 = __builtin_amdgcn_mfma_f32_16x16x32_bf16(
        a, __builtin_bit_cast(bf16x8, t1), acc1, 0, 0, 0);
    __syncthreads();
  }

  const float* b1e = b1 + (size_t)e * NI2 + n0;
  int parity = l16 & 1;
#pragma unroll
  for (int s2 = 0; s2 < 2; s2++) {
    f32x4 acc = s2 ? acc1 : acc0;
    int ncol = nw + s2 * 16 + l16;
    float bias = b1e[ncol];
#pragma unroll
    for (int r2 = 0; r2 < 4; r2++) {
      float v = acc[r2] + bias;
      float p = __shfl_xor(v, 1);
      int m = m16 + quad * 4 + r2;
      if (!parity && m < mcount) {
        float aa = fminf(v, LIMITF);
        float bb = fminf(fmaxf(p, -LIMITF), LIMITF);
        float sig = 1.0f / (1.0f + __expf(-ALPHAF * aa));
        float sval = aa * sig * (bb + 1.0f);
        s_buf[(size_t)(rowbase + m) * NI + ((n0 + ncol) >> 1)] = f2bf(sval);
      }
    }
  }
}

// ---------------- FFN2: y = s @ w2 + b2 ; out += gate*y ----------------
__global__ __launch_bounds__(256) void k_ffn2(
    const unsigned short* __restrict__ s_buf, const float* __restrict__ w2,
    const float* __restrict__ b2, const int* __restrict__ counts,
    const int* __restrict__ offsets, const int* __restrict__ rows_tok,
    const float* __restrict__ rows_gate, float* __restrict__ out) {
  int e = blockIdx.y;
  int cnt = counts[e];
  int m0 = blockIdx.z * 32;
  if (m0 >= cnt) return;
  int rowbase = offsets[e] + m0;
  int mcount = min(32, cnt - m0);
  int n0 = blockIdx.x * 64;
  int tid = threadIdx.x;

  __shared__ int tok_s[32];
  __shared__ float gate_s[32];
  __shared__ __align__(16) unsigned short lds_a[32 * 32];
  __shared__ unsigned int lds_b[64 * 17];

  if (tid < 32) {
    int rr = rowbase + min(tid, mcount - 1);
    tok_s[tid] = rows_tok[rr];
    gate_s[tid] = rows_gate[rr];
  }
  __syncthreads();

  const int wave = tid >> 6, lane = tid & 63;
  const int quad = lane >> 4, l16 = lane & 15;
  const int m16 = (wave & 1) * 16;
  const int nw = (wave >> 1) * 32;

  f32x4 acc0 = {0.f, 0.f, 0.f, 0.f}, acc1 = {0.f, 0.f, 0.f, 0.f};

  const float* w2e = w2 + (size_t)e * NI * NH + n0;
  const int ar = tid >> 3, ac = (tid & 7) * 4;
  const int bn = tid & 63, bk0 = (tid >> 6) * 2;

  for (int k0 = 0; k0 < NI; k0 += 32) {
    int arow = rowbase + min(ar, mcount - 1);
    uint2 av = *reinterpret_cast<const uint2*>(s_buf + (size_t)arow * NI + k0 + ac);
    *reinterpret_cast<uint2*>(&lds_a[ar * 32 + ac]) = av;
#pragma unroll
    for (int it = 0; it < 4; it++) {
      int kk = bk0 + it * 8;
      float f0 = w2e[(size_t)(k0 + kk) * NH + bn];
      float f1 = w2e[(size_t)(k0 + kk + 1) * NH + bn];
      lds_b[bn * 17 + (kk >> 1)] =
          (unsigned int)f2bf(f0) | ((unsigned int)f2bf(f1) << 16);
    }
    __syncthreads();
    bf16x8 a = *reinterpret_cast<const bf16x8*>(&lds_a[(m16 + l16) * 32 + quad * 8]);
    const unsigned int* bp0 = &lds_b[(nw + l16) * 17 + quad * 4];
    uint4 t0; t0.x = bp0[0]; t0.y = bp0[1]; t0.z = bp0[2]; t0.w = bp0[3];
    acc0 = __builtin_amdgcn_mfma_f32_16x16x32_bf16(
        a, __builtin_bit_cast(bf16x8, t0), acc0, 0, 0, 0);
    const unsigned int* bp1 = &lds_b[(nw + 16 + l16) * 17 + quad * 4];
    uint4 t1; t1.x = bp1[0]; t1.y = bp1[1]; t1.z = bp1[2]; t1.w = bp1[3];
    acc1 = __builtin_amdgcn_mfma_f32_16x16x32_bf16(
        a, __builtin_bit_cast(bf16x8, t1), acc1, 0, 0, 0);
    __syncthreads();
  }

  const float* b2e = b2 + (size_t)e * NH + n0;
#pragma unroll
  for (int s2 = 0; s2 < 2; s2++) {
    f32x4 acc = s2 ? acc1 : acc0;
    int ncol = nw + s2 * 16 + l16;
    float bias = b2e[ncol];
#pragma unroll
    for (int r2 = 0; r2 < 4; r2++) {
      int m = m16 + quad * 4 + r2;
      if (m < mcount) {
        float y = acc[r2] + bias;
        atomicAdd(&out[(size_t)tok_s[m] * NH + n0 + ncol], gate_s[m] * y);
      }
    }
  }
}

extern "C" void kernel_launch(void* const* d_in, const int* in_sizes, int n_in,
                              void* d_out, int out_size, void* d_ws, size_t ws_size,
                              hipStream_t stream) {
  const float* x   = (const float*)d_in[0];
  const float* nsc = (const float*)d_in[1];
  const float* wg  = (const float*)d_in[2];
  const float* bg  = (const float*)d_in[3];
  const float* w1  = (const float*)d_in[4];
  const float* b1  = (const float*)d_in[5];
  const float* w2  = (const float*)d_in[6];
  const float* b2  = (const float*)d_in[7];
  float* out = (float*)d_out;
  char* ws = (char*)d_ws;

  int*   counts    = (int*)(ws + 0);
  int*   offsets   = (int*)(ws + 64);
  int*   cursor    = (int*)(ws + 128);
  int*   topk_idx  = (int*)(ws + 1024);
  float* topk_gate = (float*)(ws + 1024 + 16384);
  int*   rows_tok  = (int*)(ws + 1024 + 32768);
  float* rows_gate = (float*)(ws + 1024 + 49152);
  unsigned short* xn    = (unsigned short*)(ws + 131072);           // 2 MB
  unsigned short* s_buf = (unsigned short*)(ws + 4 * 1024 * 1024);  // 8 MB

  hipMemsetAsync(ws, 0, 256, stream);
  k_init<<<NT * NH / 1024, 256, 0, stream>>>(x, out);
  k_norm_router<<<NT, 256, 0, stream>>>(x, nsc, wg, bg, xn, topk_idx, topk_gate,
                                        counts);
  k_scan<<<1, 64, 0, stream>>>(counts, offsets, cursor);
  k_fill<<<16, 256, 0, stream>>>(topk_idx, topk_gate, cursor, rows_tok, rows_gate);
  k_ffn1<<<dim3(NI2 / 64, NE, 32), 256, 0, stream>>>(xn, w1, b1, counts, offsets,
                                                     rows_tok, s_buf);
  k_ffn2<<<dim3(NH / 64, NE, 32), 256, 0, stream>>>(s_buf, w2, b2, counts, offsets,
                                                    rows_tok, rows_gate, out);
}

// Round 2
// 453.303 us; speedup vs baseline: 1.0684x; 1.0684x over previous
//
#include <hip/hip_runtime.h>

#define NH 1024   // hidden
#define NI2 2048  // 2*intermediate
#define NI 1024   // intermediate
#define NE 16     // experts
#define NT 1024   // tokens (2*512)

static constexpr float LIMITF = 7.0f;
static constexpr float ALPHAF = 1.702f;
static constexpr float EPSF = 1e-5f;

typedef short bf16x8 __attribute__((ext_vector_type(8)));
typedef float f32x16 __attribute__((ext_vector_type(16)));

__device__ __forceinline__ unsigned short f2bf(float f) {
  unsigned int u = __builtin_bit_cast(unsigned int, f);
  u = (u + 0x7FFFu + ((u >> 16) & 1u)) >> 16;
  return (unsigned short)u;
}

// ---------------- out = x (residual base) ----------------
__global__ __launch_bounds__(256) void k_init(const float* __restrict__ x,
                                              float* __restrict__ out) {
  int i = blockIdx.x * 256 + threadIdx.x;
  reinterpret_cast<float4*>(out)[i] = reinterpret_cast<const float4*>(x)[i];
}

// ---------------- RMSNorm + router ----------------
__global__ __launch_bounds__(256) void k_norm_router(
    const float* __restrict__ x, const float* __restrict__ nsc,
    const float* __restrict__ wg, const float* __restrict__ bg,
    unsigned short* __restrict__ xn, int* __restrict__ topk_idx,
    float* __restrict__ topk_gate, int* __restrict__ counts) {
  int t = blockIdx.x;
  int tid = threadIdx.x;
  int wave = tid >> 6, lane = tid & 63;

  float4 v = reinterpret_cast<const float4*>(x + (size_t)t * NH)[tid];
  float ss = v.x * v.x + v.y * v.y + v.z * v.z + v.w * v.w;
  for (int off = 32; off; off >>= 1) ss += __shfl_xor(ss, off);

  __shared__ float red[4];
  __shared__ float redl[4][16];
  __shared__ float logits_s[16];
  if (lane == 0) red[wave] = ss;
  __syncthreads();
  float tot = red[0] + red[1] + red[2] + red[3];
  float r = rsqrtf(tot * (1.0f / NH) + EPSF);

  float4 sc = reinterpret_cast<const float4*>(nsc)[tid];
  float xv[4];
  xv[0] = v.x * r * sc.x;
  xv[1] = v.y * r * sc.y;
  xv[2] = v.z * r * sc.z;
  xv[3] = v.w * r * sc.w;

  ushort4 o;
  o.x = f2bf(xv[0]); o.y = f2bf(xv[1]); o.z = f2bf(xv[2]); o.w = f2bf(xv[3]);
  reinterpret_cast<ushort4*>(xn + (size_t)t * NH)[tid] = o;

  float acc[16];
#pragma unroll
  for (int e = 0; e < 16; e++) acc[e] = 0.f;
  int hbase = tid * 4;
#pragma unroll
  for (int i = 0; i < 4; i++) {
    const float4* wr = reinterpret_cast<const float4*>(wg + (size_t)(hbase + i) * NE);
#pragma unroll
    for (int j = 0; j < 4; j++) {
      float4 w = wr[j];
      acc[j * 4 + 0] += xv[i] * w.x;
      acc[j * 4 + 1] += xv[i] * w.y;
      acc[j * 4 + 2] += xv[i] * w.z;
      acc[j * 4 + 3] += xv[i] * w.w;
    }
  }
#pragma unroll
  for (int e = 0; e < 16; e++)
    for (int off = 32; off; off >>= 1) acc[e] += __shfl_xor(acc[e], off);
  if (lane == 0) {
#pragma unroll
    for (int e = 0; e < 16; e++) redl[wave][e] = acc[e];
  }
  __syncthreads();
  if (tid < 16)
    logits_s[tid] = redl[0][tid] + redl[1][tid] + redl[2][tid] + redl[3][tid] + bg[tid];
  __syncthreads();

  if (tid == 0) {
    float vals[16];
#pragma unroll
    for (int e = 0; e < 16; e++) vals[e] = logits_s[e];
    int sel[4]; float sv[4];
    unsigned used = 0;
    for (int k = 0; k < 4; k++) {
      float best = -1e30f; int bi = 0;
      for (int e = 0; e < 16; e++) {
        if (!((used >> e) & 1u) && vals[e] > best) { best = vals[e]; bi = e; }
      }
      used |= 1u << bi; sel[k] = bi; sv[k] = best;
    }
    float g[4], ssum = 0.f;
    for (int k = 0; k < 4; k++) { g[k] = __expf(sv[k] - sv[0]); ssum += g[k]; }
    for (int k = 0; k < 4; k++) {
      topk_idx[t * 4 + k] = sel[k];
      topk_gate[t * 4 + k] = g[k] / ssum;
      atomicAdd(&counts[sel[k]], 1);
    }
  }
}

// ---------------- prefix scan over 16 experts ----------------
__global__ void k_scan(const int* __restrict__ counts, int* __restrict__ offsets,
                       int* __restrict__ cursor) {
  if (blockIdx.x == 0 && threadIdx.x == 0) {
    int o = 0;
    for (int e = 0; e < NE; e++) { offsets[e] = o; cursor[e] = o; o += counts[e]; }
  }
}

// ---------------- fill compact per-expert row lists ----------------
__global__ __launch_bounds__(256) void k_fill(const int* __restrict__ topk_idx,
                                              const float* __restrict__ topk_gate,
                                              int* __restrict__ cursor,
                                              int* __restrict__ rows_tok,
                                              float* __restrict__ rows_gate) {
  int idx = blockIdx.x * 256 + threadIdx.x;
  if (idx >= NT * 4) return;
  int e = topk_idx[idx];
  int slot = atomicAdd(&cursor[e], 1);
  rows_tok[slot] = idx >> 2;
  rows_gate[slot] = topk_gate[idx];
}

// ---------------- FFN1: one block per (expert, 32-col strip of w1) ------
// Stage full B panel (32 cols x 1024 K, bf16) in LDS once; loop all rows.
__global__ __launch_bounds__(256) void k_ffn1(
    const unsigned short* __restrict__ xn, const float* __restrict__ w1,
    const float* __restrict__ b1, const int* __restrict__ counts,
    const int* __restrict__ offsets, const int* __restrict__ rows_tok,
    unsigned short* __restrict__ s_buf) {
  int e = blockIdx.y;
  int cnt = counts[e];
  if (cnt == 0) return;
  int n0 = blockIdx.x * 32;
  int rowbase = offsets[e];
  int tid = threadIdx.x;

  // lds_b[kchunk 0..127][n 0..31][8]  (bf16) = 64 KB
  __shared__ __align__(16) unsigned short lds_b[128 * 32 * 8];

  const float* w1e = w1 + (size_t)e * (NH * NI2) + n0;
  {
    int col = tid & 31;
    int kc8 = tid >> 5;  // 0..7
    for (int p = 0; p < 16; p++) {
      int kb = p * 64 + kc8 * 8;
      float f[8];
#pragma unroll
      for (int j = 0; j < 8; j++) f[j] = w1e[(size_t)(kb + j) * NI2 + col];
      unsigned int pk[4];
#pragma unroll
      for (int j = 0; j < 4; j++)
        pk[j] = (unsigned)f2bf(f[2 * j]) | ((unsigned)f2bf(f[2 * j + 1]) << 16);
      *reinterpret_cast<uint4*>(&lds_b[(size_t)((kb >> 3) * 32 + col) * 8]) =
          *reinterpret_cast<const uint4*>(pk);
    }
  }
  __syncthreads();

  int lane = tid & 63;
  int wave = tid >> 6;
  int lrow = lane & 31;
  int khalf = lane >> 5;

  float bias = b1[(size_t)e * NI2 + n0 + lrow];
  int parity = lrow & 1;

  for (int m0 = 0; m0 < cnt; m0 += 256) {
    int tb0 = m0 + wave * 32;
    int tb1 = m0 + 128 + wave * 32;
    int tok0 = rows_tok[rowbase + min(tb0 + lrow, cnt - 1)];
    const unsigned short* a0p = xn + (size_t)tok0 * NH + khalf * 8;

    f32x16 acc0 = {0.f,0.f,0.f,0.f,0.f,0.f,0.f,0.f,0.f,0.f,0.f,0.f,0.f,0.f,0.f,0.f};
    f32x16 acc1 = {0.f,0.f,0.f,0.f,0.f,0.f,0.f,0.f,0.f,0.f,0.f,0.f,0.f,0.f,0.f,0.f};
    bool dual = (m0 + 128) < cnt;

    if (dual) {
      int tok1 = rows_tok[rowbase + min(tb1 + lrow, cnt - 1)];
      const unsigned short* a1p = xn + (size_t)tok1 * NH + khalf * 8;
#pragma unroll 4
      for (int k2 = 0; k2 < 64; k2++) {
        bf16x8 av0 = *reinterpret_cast<const bf16x8*>(a0p + k2 * 16);
        bf16x8 av1 = *reinterpret_cast<const bf16x8*>(a1p + k2 * 16);
        bf16x8 bv = *reinterpret_cast<const bf16x8*>(
            &lds_b[(size_t)((k2 * 2 + khalf) * 32 + lrow) * 8]);
        acc0 = __builtin_amdgcn_mfma_f32_32x32x16_bf16(av0, bv, acc0, 0, 0, 0);
        acc1 = __builtin_amdgcn_mfma_f32_32x32x16_bf16(av1, bv, acc1, 0, 0, 0);
      }
    } else {
#pragma unroll 4
      for (int k2 = 0; k2 < 64; k2++) {
        bf16x8 av0 = *reinterpret_cast<const bf16x8*>(a0p + k2 * 16);
        bf16x8 bv = *reinterpret_cast<const bf16x8*>(
            &lds_b[(size_t)((k2 * 2 + khalf) * 32 + lrow) * 8]);
        acc0 = __builtin_amdgcn_mfma_f32_32x32x16_bf16(av0, bv, acc0, 0, 0, 0);
      }
    }

#pragma unroll
    for (int t2 = 0; t2 < 2; t2++) {
      if (t2 == 1 && !dual) break;
      f32x16 acc = t2 ? acc1 : acc0;
      int tb = t2 ? tb1 : tb0;
#pragma unroll
      for (int reg = 0; reg < 16; reg++) {
        float v = acc[reg] + bias;
        float p = __shfl_xor(v, 1);
        int row = (reg & 3) + 8 * (reg >> 2) + 4 * khalf;
        int m = tb + row;
        if (!parity && m < cnt) {
          float aa = fminf(v, LIMITF);
          float bb = fminf(fmaxf(p, -LIMITF), LIMITF);
          float sig = 1.0f / (1.0f + __expf(-ALPHAF * aa));
          float sval = aa * sig * (bb + 1.0f);
          s_buf[(size_t)(rowbase + m) * NI + ((n0 + lrow) >> 1)] = f2bf(sval);
        }
      }
    }
  }
}

// ---------------- FFN2: one block per (expert, 32-col strip of w2) ------
__global__ __launch_bounds__(256) void k_ffn2(
    const unsigned short* __restrict__ s_buf, const float* __restrict__ w2,
    const float* __restrict__ b2, const int* __restrict__ counts,
    const int* __restrict__ offsets, const int* __restrict__ rows_tok,
    const float* __restrict__ rows_gate, float* __restrict__ out) {
  int e = blockIdx.y;
  int cnt = counts[e];
  if (cnt == 0) return;
  int n0 = blockIdx.x * 32;
  int rowbase = offsets[e];
  int tid = threadIdx.x;

  __shared__ __align__(16) unsigned short lds_b[128 * 32 * 8];  // 64 KB

  const float* w2e = w2 + (size_t)e * (NI * NH) + n0;
  {
    int col = tid & 31;
    int kc8 = tid >> 5;
    for (int p = 0; p < 16; p++) {
      int kb = p * 64 + kc8 * 8;
      float f[8];
#pragma unroll
      for (int j = 0; j < 8; j++) f[j] = w2e[(size_t)(kb + j) * NH + col];
      unsigned int pk[4];
#pragma unroll
      for (int j = 0; j < 4; j++)
        pk[j] = (unsigned)f2bf(f[2 * j]) | ((unsigned)f2bf(f[2 * j + 1]) << 16);
      *reinterpret_cast<uint4*>(&lds_b[(size_t)((kb >> 3) * 32 + col) * 8]) =
          *reinterpret_cast<const uint4*>(pk);
    }
  }
  __syncthreads();

  int lane = tid & 63;
  int wave = tid >> 6;
  int lrow = lane & 31;
  int khalf = lane >> 5;

  float b2v = b2[(size_t)e * NH + n0 + lrow];

  for (int m0 = 0; m0 < cnt; m0 += 256) {
    int tb0 = m0 + wave * 32;
    int tb1 = m0 + 128 + wave * 32;
    int r0 = rowbase + min(tb0 + lrow, cnt - 1);
    const unsigned short* a0p = s_buf + (size_t)r0 * NI + khalf * 8;

    f32x16 acc0 = {0.f,0.f,0.f,0.f,0.f,0.f,0.f,0.f,0.f,0.f,0.f,0.f,0.f,0.f,0.f,0.f};
    f32x16 acc1 = {0.f,0.f,0.f,0.f,0.f,0.f,0.f,0.f,0.f,0.f,0.f,0.f,0.f,0.f,0.f,0.f};
    bool dual = (m0 + 128) < cnt;

    if (dual) {
      int r1 = rowbase + min(tb1 + lrow, cnt - 1);
      const unsigned short* a1p = s_buf + (size_t)r1 * NI + khalf * 8;
#pragma unroll 4
      for (int k2 = 0; k2 < 64; k2++) {
        bf16x8 av0 = *reinterpret_cast<const bf16x8*>(a0p + k2 * 16);
        bf16x8 av1 = *reinterpret_cast<const bf16x8*>(a1p + k2 * 16);
        bf16x8 bv = *reinterpret_cast<const bf16x8*>(
            &lds_b[(size_t)((k2 * 2 + khalf) * 32 + lrow) * 8]);
        acc0 = __builtin_amdgcn_mfma_f32_32x32x16_bf16(av0, bv, acc0, 0, 0, 0);
        acc1 = __builtin_amdgcn_mfma_f32_32x32x16_bf16(av1, bv, acc1, 0, 0, 0);
      }
    } else {
#pragma unroll 4
      for (int k2 = 0; k2 < 64; k2++) {
        bf16x8 av0 = *reinterpret_cast<const bf16x8*>(a0p + k2 * 16);
        bf16x8 bv = *reinterpret_cast<const bf16x8*>(
            &lds_b[(size_t)((k2 * 2 + khalf) * 32 + lrow) * 8]);
        acc0 = __builtin_amdgcn_mfma_f32_32x32x16_bf16(av0, bv, acc0, 0, 0, 0);
      }
    }

#pragma unroll
    for (int t2 = 0; t2 < 2; t2++) {
      if (t2 == 1 && !dual) break;
      f32x16 acc = t2 ? acc1 : acc0;
      int tb = t2 ? tb1 : tb0;
#pragma unroll
      for (int reg = 0; reg < 16; reg++) {
        int row = (reg & 3) + 8 * (reg >> 2) + 4 * khalf;
        int m = tb + row;
        if (m < cnt) {
          int rr = rowbase + m;
          int tok = rows_tok[rr];
          float g = rows_gate[rr];
          atomicAdd(&out[(size_t)tok * NH + n0 + lrow], g * (acc[reg] + b2v));
        }
      }
    }
  }
}

extern "C" void kernel_launch(void* const* d_in, const int* in_sizes, int n_in,
                              void* d_out, int out_size, void* d_ws, size_t ws_size,
                              hipStream_t stream) {
  const float* x   = (const float*)d_in[0];
  const float* nsc = (const float*)d_in[1];
  const float* wg  = (const float*)d_in[2];
  const float* bg  = (const float*)d_in[3];
  const float* w1  = (const float*)d_in[4];
  const float* b1  = (const float*)d_in[5];
  const float* w2  = (const float*)d_in[6];
  const float* b2  = (const float*)d_in[7];
  float* out = (float*)d_out;
  char* ws = (char*)d_ws;

  int*   counts    = (int*)(ws + 0);
  int*   offsets   = (int*)(ws + 64);
  int*   cursor    = (int*)(ws + 128);
  int*   topk_idx  = (int*)(ws + 1024);
  float* topk_gate = (float*)(ws + 1024 + 16384);
  int*   rows_tok  = (int*)(ws + 1024 + 32768);
  float* rows_gate = (float*)(ws + 1024 + 49152);
  unsigned short* xn    = (unsigned short*)(ws + 131072);           // 2 MB
  unsigned short* s_buf = (unsigned short*)(ws + 4 * 1024 * 1024);  // 8 MB

  hipMemsetAsync(ws, 0, 256, stream);
  k_init<<<NT * NH / 1024, 256, 0, stream>>>(x, out);
  k_norm_router<<<NT, 256, 0, stream>>>(x, nsc, wg, bg, xn, topk_idx, topk_gate,
                                        counts);
  k_scan<<<1, 64, 0, stream>>>(counts, offsets, cursor);
  k_fill<<<16, 256, 0, stream>>>(topk_idx, topk_gate, cursor, rows_tok, rows_gate);
  k_ffn1<<<dim3(NI2 / 32, NE), 256, 0, stream>>>(xn, w1, b1, counts, offsets,
                                                 rows_tok, s_buf);
  k_ffn2<<<dim3(NH / 32, NE), 256, 0, stream>>>(s_buf, w2, b2, counts, offsets,
                                                rows_tok, rows_gate, out);
}